// Round 3
// baseline (685.394 us; speedup 1.0000x reference)
//
#include <hip/hip_runtime.h>
#include <hip/hip_cooperative_groups.h>

namespace cg = cooperative_groups;

#define BATCH 16

// ---------------------------------------------------------------------------
// Quad-lane primitives: all cross-lane traffic via DPP quad_perm (VALU pipe).
// ---------------------------------------------------------------------------
template <int CTRL>
__device__ __forceinline__ float qperm(float x) {
  int xi = __float_as_int(x);
  return __int_as_float(__builtin_amdgcn_update_dpp(xi, xi, CTRL, 0xF, 0xF, true));
}

__device__ __forceinline__ float4 f4fma(float s, float4 a, float4 c) {
  c.x = fmaf(s, a.x, c.x);
  c.y = fmaf(s, a.y, c.y);
  c.z = fmaf(s, a.z, c.z);
  c.w = fmaf(s, a.w, c.w);
  return c;
}

// D=16 MPS chain (4 steps), vec distributed 4 components per quad lane.
__device__ __forceinline__ void mps16_chain(const float* A, int jq,
                                            const float tt[4], float vec[4]) {
#pragma unroll
  for (int s = 0; s < 4; s++) {
    const float4* A0v = (const float4*)(A + s * 512) + jq;
    const float4* A1v = A0v + 64;  // f=1 block (+256 floats)
    float4 q0 = {0.f, 0.f, 0.f, 0.f}, q1 = {0.f, 0.f, 0.f, 0.f};
#define ISTEP(i)                                         \
  {                                                      \
    float sv = qperm<(((i) >> 2) * 0x55)>(vec[(i) & 3]); \
    q0 = f4fma(sv, A0v[(i) * 4], q0);                    \
    q1 = f4fma(sv, A1v[(i) * 4], q1);                    \
  }
    ISTEP(0) ISTEP(1) ISTEP(2) ISTEP(3)
    ISTEP(4) ISTEP(5) ISTEP(6) ISTEP(7)
    ISTEP(8) ISTEP(9) ISTEP(10) ISTEP(11)
    ISTEP(12) ISTEP(13) ISTEP(14) ISTEP(15)
#undef ISTEP
    float ph = tt[s], om = 1.0f - ph;
    vec[0] = ph * q0.x + om * q1.x;
    vec[1] = ph * q0.y + om * q1.y;
    vec[2] = ph * q0.z + om * q1.z;
    vec[3] = ph * q0.w + om * q1.w;
  }
}

// ---------------------------------------------------------------------------
// Generic 4-lane fused d+i unit (pointer address-space agnostic; used by the
// tail's L6 with LDS-resident params). XS: x element stride.
// ---------------------------------------------------------------------------
template <int H, int XS>
__device__ __forceinline__ float fused_di_quad(
    const float* xb, int p, int jq, const float* dA, const float* dv,
    const float* dw, const float* iA, const float* iv, const float* iw) {
  constexpr int NH = (H - 2) / 2;
  constexpr int W2 = H / 2;
  int pi = p / W2, pj = p % W2;
  int r = 2 * pi + (jq >> 1), c = 2 * pj + (jq & 1);
  float tcell;
  bool border = (r == 0) | (r == H - 1) | (c == 0) | (c == H - 1);
  if (border) {
    tcell = xb[(r * H + c) * XS];
  } else {
    int dpi = (r - 1) >> 1, dpj = (c - 1) >> 1;
    int sd = ((r - 1) & 1) * 2 + ((c - 1) & 1);
    int dp = dpi * NH + dpj;
    int R0 = 1 + 2 * dpi, C0 = 1 + 2 * dpj;
    float tins[4];
    tins[0] = xb[(R0 * H + C0) * XS];
    tins[1] = xb[(R0 * H + C0 + 1) * XS];
    tins[2] = xb[((R0 + 1) * H + C0) * XS];
    tins[3] = xb[((R0 + 1) * H + C0 + 1) * XS];
    const float4* Av = (const float4*)(dA + dp * 128);  // [s][f][4][4]
    float4 dvv = *(const float4*)(dv + dp * 4);
    float v0 = dvv.x, v1 = dvv.y, v2 = dvv.z, v3 = dvv.w;
#pragma unroll
    for (int s = 0; s < 4; s++) {
      const float4* A0 = Av + s * 8;
      float4 q0 = {0.f, 0.f, 0.f, 0.f}, q1 = {0.f, 0.f, 0.f, 0.f};
      q0 = f4fma(v0, A0[0], q0);
      q0 = f4fma(v1, A0[1], q0);
      q0 = f4fma(v2, A0[2], q0);
      q0 = f4fma(v3, A0[3], q0);
      q1 = f4fma(v0, A0[4], q1);
      q1 = f4fma(v1, A0[5], q1);
      q1 = f4fma(v2, A0[6], q1);
      q1 = f4fma(v3, A0[7], q1);
      float ph = tins[s], om = 1.0f - ph;
      v0 = ph * q0.x + om * q1.x;
      v1 = ph * q0.y + om * q1.y;
      v2 = ph * q0.z + om * q1.z;
      v3 = ph * q0.w + om * q1.w;
    }
    const float* wp = dw + dp * 16 + sd;
    float y = v0 * wp[0];
    y = fmaf(v1, wp[4], y);
    y = fmaf(v2, wp[8], y);
    y = fmaf(v3, wp[12], y);
    tcell = fmaxf(y, 0.0f);
  }
  float tt[4];
  tt[0] = qperm<0x00>(tcell);
  tt[1] = qperm<0x55>(tcell);
  tt[2] = qperm<0xAA>(tcell);
  tt[3] = qperm<0xFF>(tcell);
  float4 vv = *(const float4*)(iv + p * 16 + 4 * jq);
  float vec[4] = {vv.x, vv.y, vv.z, vv.w};
  mps16_chain(iA + (size_t)p * 2048, jq, tt, vec);
  float4 wv = *(const float4*)(iw + p * 16 + 4 * jq);
  float partial = vec[0] * wv.x;
  partial = fmaf(vec[1], wv.y, partial);
  partial = fmaf(vec[2], wv.z, partial);
  partial = fmaf(vec[3], wv.w, partial);
  partial += qperm<0xB1>(partial);
  partial += qperm<0x4E>(partial);
  return fmaxf(partial, 0.0f);
}

// ---------------------------------------------------------------------------
// LDS layout (floats). 39360 B total -> 4 blocks/CU ceiling by LDS.
// ---------------------------------------------------------------------------
#define OFF_IA 0      // 4 x 2048
#define OFF_IV 8192   // 4 x 16
#define OFF_IW 8256   // 4 x 16
#define OFF_DA 8320   // 10 slots x 132 (128 + 4 pad)
#define OFF_DV 9640   // 10 x 4
#define OFF_DW 9680   // 10 x 16
#define LDS_TOT 9840
#define OFF_X6 (OFF_DA + 264)   // 256 fl, overlays unused dA slots (tail only)
#define OFF_H6 (OFF_DA + 1056)  // 64 fl (tail only)

// ---------------------------------------------------------------------------
// One staged level phase: 4 consecutive patches of one patch-row per block.
// RAW: read x as [b][H][H]; else read [cell][16b]. Output hn: [p][16b].
// ---------------------------------------------------------------------------
template <int H, bool RAW>
__device__ void level_phase(float* lds, const float* __restrict__ xin,
                            float* __restrict__ hn,
                            const float* __restrict__ dA,
                            const float* __restrict__ dv,
                            const float* __restrict__ dw,
                            const float* __restrict__ iA,
                            const float* __restrict__ iv,
                            const float* __restrict__ iw, int p0) {
  constexpr int W2 = H / 2, NH = (H - 2) / 2;
  float4* l4 = (float4*)lds;
  const int tid = threadIdx.x;
  const int pi = p0 / W2, pj0 = p0 % W2;
  const int jq = tid & 3, b = (tid >> 2) & 15, w = tid >> 6;
  const int pj = pj0 + w;
  const int r = 2 * pi + (jq >> 1), c = 2 * pj + (jq & 1);
  const bool border = (r == 0) | (r == H - 1) | (c == 0) | (c == H - 1);
  const int dpi = (r - 1) >> 1, dpj = (c - 1) >> 1;

  // ---- x preload (global only; issues before staging, hides under it)
  float xv0, xv1, xv2, xv3;
  if (RAW) {
    const float* xb = xin + b * H * H;
    if (border) {
      xv0 = xb[r * H + c];
    } else {
      int R0 = 1 + 2 * dpi, C0 = 1 + 2 * dpj;
      xv0 = xb[R0 * H + C0];
      xv1 = xb[R0 * H + C0 + 1];
      xv2 = xb[(R0 + 1) * H + C0];
      xv3 = xb[(R0 + 1) * H + C0 + 1];
    }
  } else {
    if (border) {
      xv0 = xin[(r * H + c) * 16 + b];
    } else {
      int R0 = 1 + 2 * dpi, C0 = 1 + 2 * dpj;
      xv0 = xin[(R0 * H + C0) * 16 + b];
      xv1 = xin[(R0 * H + C0 + 1) * 16 + b];
      xv2 = xin[((R0 + 1) * H + C0) * 16 + b];
      xv3 = xin[((R0 + 1) * H + C0 + 1) * 16 + b];
    }
  }

  __syncthreads();  // LDS free from previous phase/round

  // ---- stage phase -------------------------------------------------------
  {
    const float4* iA4 = (const float4*)iA + p0 * 512;
    float4 ra[8];
#pragma unroll
    for (int k = 0; k < 8; k++) ra[k] = iA4[tid + k * 256];

    float4 rd0, rd1;
    int sl0, gr0, sl1, gr1;
    const bool md1 = tid < 64;
    {
      int g = tid;
      int rs = g / 160, rem = g % 160, cs = rem / 32;
      gr0 = rem % 32;
      int di = min(max(pi - 1 + rs, 0), NH - 1);
      int dj = min(max(pj0 - 1 + cs, 0), NH - 1);
      sl0 = rs * 5 + cs;
      rd0 = *((const float4*)dA + (di * NH + dj) * 32 + gr0);
    }
    if (md1) {
      int g = tid + 256;
      int rs = g / 160, rem = g % 160, cs = rem / 32;
      gr1 = rem % 32;
      int di = min(max(pi - 1 + rs, 0), NH - 1);
      int dj = min(max(pj0 - 1 + cs, 0), NH - 1);
      sl1 = rs * 5 + cs;
      rd1 = *((const float4*)dA + (di * NH + dj) * 32 + gr1);
    }
    float4 rv;
    const bool mv = tid < 10;
    if (mv) {
      int rs = tid / 5, cs = tid % 5;
      int di = min(max(pi - 1 + rs, 0), NH - 1);
      int dj = min(max(pj0 - 1 + cs, 0), NH - 1);
      rv = *((const float4*)dv + (di * NH + dj));
    }
    float4 rw;
    const bool mw = tid < 40;
    if (mw) {
      int rs = tid / 20, rem = tid % 20, cs = rem / 4, gr = rem % 4;
      int di = min(max(pi - 1 + rs, 0), NH - 1);
      int dj = min(max(pj0 - 1 + cs, 0), NH - 1);
      rw = *((const float4*)dw + (di * NH + dj) * 4 + gr);
    }
    float4 rvv, rww;
    const bool mi = tid < 16;
    if (mi) {
      rvv = *((const float4*)iv + p0 * 4 + tid);
      rww = *((const float4*)iw + p0 * 4 + tid);
    }
#pragma unroll
    for (int k = 0; k < 8; k++) l4[OFF_IA / 4 + tid + k * 256] = ra[k];
    l4[OFF_DA / 4 + sl0 * 33 + gr0] = rd0;
    if (md1) l4[OFF_DA / 4 + sl1 * 33 + gr1] = rd1;
    if (mv) l4[OFF_DV / 4 + tid] = rv;
    if (mw) l4[OFF_DW / 4 + tid] = rw;
    if (mi) l4[OFF_IV / 4 + tid] = rvv;
    if (mi) l4[OFF_IW / 4 + tid] = rww;
  }
  __syncthreads();

  // ---- compute phase -----------------------------------------------------
  float tcell;
  if (border) {
    tcell = xv0;
  } else {
    int sd = ((r - 1) & 1) * 2 + ((c - 1) & 1);
    int slot = (dpi - pi + 1) * 5 + (dpj - pj0 + 1);
    const float4* Av = (const float4*)(lds + OFF_DA + slot * 132);
    float4 dvv = *(const float4*)(lds + OFF_DV + slot * 4);
    float v0 = dvv.x, v1 = dvv.y, v2 = dvv.z, v3 = dvv.w;
    float tins[4] = {xv0, xv1, xv2, xv3};
#pragma unroll
    for (int s = 0; s < 4; s++) {
      const float4* A0 = Av + s * 8;
      float4 q0 = {0.f, 0.f, 0.f, 0.f}, q1 = {0.f, 0.f, 0.f, 0.f};
      q0 = f4fma(v0, A0[0], q0);
      q0 = f4fma(v1, A0[1], q0);
      q0 = f4fma(v2, A0[2], q0);
      q0 = f4fma(v3, A0[3], q0);
      q1 = f4fma(v0, A0[4], q1);
      q1 = f4fma(v1, A0[5], q1);
      q1 = f4fma(v2, A0[6], q1);
      q1 = f4fma(v3, A0[7], q1);
      float ph = tins[s], om = 1.0f - ph;
      v0 = ph * q0.x + om * q1.x;
      v1 = ph * q0.y + om * q1.y;
      v2 = ph * q0.z + om * q1.z;
      v3 = ph * q0.w + om * q1.w;
    }
    const float* wp = lds + OFF_DW + slot * 16 + sd;
    float y = v0 * wp[0];
    y = fmaf(v1, wp[4], y);
    y = fmaf(v2, wp[8], y);
    y = fmaf(v3, wp[12], y);
    tcell = fmaxf(y, 0.0f);
  }
  float tt[4];
  tt[0] = qperm<0x00>(tcell);
  tt[1] = qperm<0x55>(tcell);
  tt[2] = qperm<0xAA>(tcell);
  tt[3] = qperm<0xFF>(tcell);
  float4 vv = *(const float4*)(lds + OFF_IV + w * 16 + 4 * jq);
  float vec[4] = {vv.x, vv.y, vv.z, vv.w};
  mps16_chain(lds + OFF_IA + w * 2048, jq, tt, vec);
  float4 wv = *(const float4*)(lds + OFF_IW + w * 16 + 4 * jq);
  float partial = vec[0] * wv.x;
  partial = fmaf(vec[1], wv.y, partial);
  partial = fmaf(vec[2], wv.z, partial);
  partial = fmaf(vec[3], wv.w, partial);
  partial += qperm<0xB1>(partial);
  partial += qperm<0x4E>(partial);
  if (jq == 0) hn[(p0 + w) * 16 + b] = fmaxf(partial, 0.0f);
}

// ---------------------------------------------------------------------------
// Mega-kernel args: P[0..35] = per-level dA,dv,dw,iA,iv,iw; P[36..38]=fA,fv,fw
// ---------------------------------------------------------------------------
struct MegaArgs {
  const float* x;
  const float* P[39];
  float* h1;
  float* h2;
  float* h3;
  float* h4;
  float* h5;
  float* out;
};

// ---------------------------------------------------------------------------
// Tail phase (block 0 only): L6 (H=4, all 16 b in one block) + final head,
// with all params staged into LDS.
// ---------------------------------------------------------------------------
__device__ void tail_phase(float* lds, const MegaArgs& a) {
  float4* l4 = (float4*)lds;
  const int tid = threadIdx.x;
  const float* d6A = a.P[30];
  const float* d6v = a.P[31];
  const float* d6w = a.P[32];
  const float* i6A = a.P[33];
  const float* i6v = a.P[34];
  const float* i6w = a.P[35];
  const float* fA = a.P[36];
  const float* fv = a.P[37];
  const float* fw = a.P[38];
  __syncthreads();
  {
    const float4* g = (const float4*)i6A;
    float4 ra[8];
#pragma unroll
    for (int k = 0; k < 8; k++) ra[k] = g[tid + k * 256];
    float4 rdA;
    const bool mA = tid < 32;
    if (mA) rdA = ((const float4*)d6A)[tid];
    float4 rdv;
    const bool mdv = tid == 0;
    if (mdv) rdv = ((const float4*)d6v)[0];
    float4 rdw;
    const bool mdw = tid < 4;
    if (mdw) rdw = ((const float4*)d6w)[tid];
    float4 riv, riw;
    const bool mi = tid < 16;
    if (mi) {
      riv = ((const float4*)i6v)[tid];
      riw = ((const float4*)i6w)[tid];
    }
    float x6v = a.h5[(tid & 15) * 16 + (tid >> 4)];  // [b][cell] in LDS
#pragma unroll
    for (int k = 0; k < 8; k++) l4[OFF_IA / 4 + tid + k * 256] = ra[k];
    if (mA) l4[OFF_DA / 4 + tid] = rdA;  // contiguous slot 0
    if (mdv) l4[OFF_DV / 4] = rdv;
    if (mdw) l4[OFF_DW / 4 + tid] = rdw;
    if (mi) {
      l4[OFF_IV / 4 + tid] = riv;
      l4[OFF_IW / 4 + tid] = riw;
    }
    lds[OFF_X6 + tid] = x6v;
  }
  __syncthreads();
  {
    int jq = tid & 3, p = (tid >> 2) & 3, b = tid >> 4;
    float o = fused_di_quad<4, 1>(lds + OFF_X6 + b * 16, p, jq, lds + OFF_DA,
                                  lds + OFF_DV, lds + OFF_DW, lds + OFF_IA,
                                  lds + OFF_IV, lds + OFF_IW);
    if (jq == 0) lds[OFF_H6 + b * 4 + p] = o;
  }
  __syncthreads();
  {
    const float4* g = (const float4*)fA;  // 512 granules
    float4 r0 = g[tid], r1 = g[tid + 256];
    l4[OFF_IA / 4 + tid] = r0;
    l4[OFF_IA / 4 + tid + 256] = r1;
  }
  __syncthreads();
  if (tid < 64) {
    int jq = tid & 3, b = tid >> 2;
    float tt[4] = {lds[OFF_H6 + b * 4 + 0], lds[OFF_H6 + b * 4 + 1],
                   lds[OFF_H6 + b * 4 + 2], lds[OFF_H6 + b * 4 + 3]};
    float4 vv = *(const float4*)(fv + 4 * jq);
    float vec[4] = {vv.x, vv.y, vv.z, vv.w};
    mps16_chain(lds + OFF_IA, jq, tt, vec);
    float acc[10];
#pragma unroll
    for (int o = 0; o < 10; o++) acc[o] = 0.f;
#pragma unroll
    for (int k = 0; k < 4; k++)
#pragma unroll
      for (int o = 0; o < 10; o++)
        acc[o] = fmaf(vec[k], fw[(4 * jq + k) * 10 + o], acc[o]);
#pragma unroll
    for (int o = 0; o < 10; o++) {
      acc[o] += qperm<0xB1>(acc[o]);
      acc[o] += qperm<0x4E>(acc[o]);
    }
    if (jq == 0) {
#pragma unroll
      for (int o = 0; o < 10; o++) a.out[b * 10 + o] = fmaxf(acc[o], 0.0f);
    }
  }
}

#define LPARAMS(l)                                                    \
  a.P[6 * ((l)-1) + 0], a.P[6 * ((l)-1) + 1], a.P[6 * ((l)-1) + 2],   \
      a.P[6 * ((l)-1) + 3], a.P[6 * ((l)-1) + 4], a.P[6 * ((l)-1) + 5]

// ---------------------------------------------------------------------------
// Whole network in one cooperative launch: 512 blocks x 256 threads.
// LDS 39.4 KB -> 4 blocks/CU ceiling; co-residency needs only 2/CU.
// ---------------------------------------------------------------------------
__global__ __launch_bounds__(256) void mega_kernel(MegaArgs a) {
  __shared__ __align__(16) float lds[LDS_TOT];
  cg::grid_group grid = cg::this_grid();
  const int bid = blockIdx.x;

  // L1: H=128, 4096 patches = 512 blocks x 2 rounds x 4
  level_phase<128, true>(lds, a.x, a.h1, LPARAMS(1), bid * 8);
  level_phase<128, true>(lds, a.x, a.h1, LPARAMS(1), bid * 8 + 4);
  __threadfence();
  grid.sync();
  // L2: H=64, 1024 patches = 256 blocks x 4
  if (bid < 256) level_phase<64, false>(lds, a.h1, a.h2, LPARAMS(2), bid * 4);
  __threadfence();
  grid.sync();
  // L3: H=32, 256 patches = 64 blocks x 4
  if (bid < 64) level_phase<32, false>(lds, a.h2, a.h3, LPARAMS(3), bid * 4);
  __threadfence();
  grid.sync();
  // L4: H=16, 64 patches = 16 blocks x 4
  if (bid < 16) level_phase<16, false>(lds, a.h3, a.h4, LPARAMS(4), bid * 4);
  __threadfence();
  grid.sync();
  // L5: H=8, 16 patches = 4 blocks x 4
  if (bid < 4) level_phase<8, false>(lds, a.h4, a.h5, LPARAMS(5), bid * 4);
  __threadfence();
  grid.sync();
  // L6 + head
  if (bid == 0) tail_phase(lds, a);
}

extern "C" void kernel_launch(void* const* d_in, const int* in_sizes, int n_in,
                              void* d_out, int out_size, void* d_ws,
                              size_t ws_size, hipStream_t stream) {
  MegaArgs ma;
  ma.x = (const float*)d_in[0];
  for (int i = 0; i < 39; i++) ma.P[i] = (const float*)d_in[1 + i];
  float* ws = (float*)d_ws;
  ma.h1 = ws;              // 4096 x 16
  ma.h2 = ma.h1 + 65536;   // 1024 x 16
  ma.h3 = ma.h2 + 16384;   //  256 x 16
  ma.h4 = ma.h3 + 4096;    //   64 x 16
  ma.h5 = ma.h4 + 1024;    //   16 x 16
  ma.out = (float*)d_out;
  void* args[] = {&ma};
  hipLaunchCooperativeKernel(reinterpret_cast<void*>(mega_kernel), dim3(512),
                             dim3(256), args, 0, stream);
}

// Round 4
// 195.948 us; speedup vs baseline: 3.4978x; 3.4978x over previous
//
#include <hip/hip_runtime.h>

#define BATCH 16

// ---------------------------------------------------------------------------
// Quad-lane primitives: all cross-lane traffic via DPP quad_perm (VALU pipe).
// ---------------------------------------------------------------------------
template <int CTRL>
__device__ __forceinline__ float qperm(float x) {
  int xi = __float_as_int(x);
  return __int_as_float(__builtin_amdgcn_update_dpp(xi, xi, CTRL, 0xF, 0xF, true));
}

__device__ __forceinline__ float4 f4fma(float s, float4 a, float4 c) {
  c.x = fmaf(s, a.x, c.x);
  c.y = fmaf(s, a.y, c.y);
  c.z = fmaf(s, a.z, c.z);
  c.w = fmaf(s, a.w, c.w);
  return c;
}

// D=16 MPS chain (4 steps), vec distributed 4 components per quad lane.
// A layout: [s][f][16][16] floats. Works for LDS or global pointers.
__device__ __forceinline__ void mps16_chain(const float* A, int jq,
                                            const float tt[4], float vec[4]) {
#pragma unroll
  for (int s = 0; s < 4; s++) {
    const float4* A0v = (const float4*)(A + s * 512) + jq;
    const float4* A1v = A0v + 64;  // f=1 block (+256 floats)
    float4 q0 = {0.f, 0.f, 0.f, 0.f}, q1 = {0.f, 0.f, 0.f, 0.f};
#define ISTEP(i)                                         \
  {                                                      \
    float sv = qperm<(((i) >> 2) * 0x55)>(vec[(i) & 3]); \
    q0 = f4fma(sv, A0v[(i) * 4], q0);                    \
    q1 = f4fma(sv, A1v[(i) * 4], q1);                    \
  }
    ISTEP(0) ISTEP(1) ISTEP(2) ISTEP(3)
    ISTEP(4) ISTEP(5) ISTEP(6) ISTEP(7)
    ISTEP(8) ISTEP(9) ISTEP(10) ISTEP(11)
    ISTEP(12) ISTEP(13) ISTEP(14) ISTEP(15)
#undef ISTEP
    float ph = tt[s], om = 1.0f - ph;
    vec[0] = ph * q0.x + om * q1.x;
    vec[1] = ph * q0.y + om * q1.y;
    vec[2] = ph * q0.z + om * q1.z;
    vec[3] = ph * q0.w + om * q1.w;
  }
}

// ---------------------------------------------------------------------------
// Generic 4-lane fused d+i unit (address-space agnostic; used by the tail's
// L6 with LDS-resident params). XS: x element stride.
// ---------------------------------------------------------------------------
template <int H, int XS>
__device__ __forceinline__ float fused_di_quad(
    const float* xb, int p, int jq, const float* dA, const float* dv,
    const float* dw, const float* iA, const float* iv, const float* iw) {
  constexpr int NH = (H - 2) / 2;
  constexpr int W2 = H / 2;
  int pi = p / W2, pj = p % W2;
  int r = 2 * pi + (jq >> 1), c = 2 * pj + (jq & 1);
  float tcell;
  bool border = (r == 0) | (r == H - 1) | (c == 0) | (c == H - 1);
  if (border) {
    tcell = xb[(r * H + c) * XS];
  } else {
    int dpi = (r - 1) >> 1, dpj = (c - 1) >> 1;
    int sd = ((r - 1) & 1) * 2 + ((c - 1) & 1);
    int dp = dpi * NH + dpj;
    int R0 = 1 + 2 * dpi, C0 = 1 + 2 * dpj;
    float tins[4];
    tins[0] = xb[(R0 * H + C0) * XS];
    tins[1] = xb[(R0 * H + C0 + 1) * XS];
    tins[2] = xb[((R0 + 1) * H + C0) * XS];
    tins[3] = xb[((R0 + 1) * H + C0 + 1) * XS];
    const float4* Av = (const float4*)(dA + dp * 128);  // [s][f][4][4]
    float4 dvv = *(const float4*)(dv + dp * 4);
    float v0 = dvv.x, v1 = dvv.y, v2 = dvv.z, v3 = dvv.w;
#pragma unroll
    for (int s = 0; s < 4; s++) {
      const float4* A0 = Av + s * 8;
      float4 q0 = {0.f, 0.f, 0.f, 0.f}, q1 = {0.f, 0.f, 0.f, 0.f};
      q0 = f4fma(v0, A0[0], q0);
      q0 = f4fma(v1, A0[1], q0);
      q0 = f4fma(v2, A0[2], q0);
      q0 = f4fma(v3, A0[3], q0);
      q1 = f4fma(v0, A0[4], q1);
      q1 = f4fma(v1, A0[5], q1);
      q1 = f4fma(v2, A0[6], q1);
      q1 = f4fma(v3, A0[7], q1);
      float ph = tins[s], om = 1.0f - ph;
      v0 = ph * q0.x + om * q1.x;
      v1 = ph * q0.y + om * q1.y;
      v2 = ph * q0.z + om * q1.z;
      v3 = ph * q0.w + om * q1.w;
    }
    const float* wp = dw + dp * 16 + sd;
    float y = v0 * wp[0];
    y = fmaf(v1, wp[4], y);
    y = fmaf(v2, wp[8], y);
    y = fmaf(v3, wp[12], y);
    tcell = fmaxf(y, 0.0f);
  }
  float tt[4];
  tt[0] = qperm<0x00>(tcell);
  tt[1] = qperm<0x55>(tcell);
  tt[2] = qperm<0xAA>(tcell);
  tt[3] = qperm<0xFF>(tcell);
  float4 vv = *(const float4*)(iv + p * 16 + 4 * jq);
  float vec[4] = {vv.x, vv.y, vv.z, vv.w};
  mps16_chain(iA + (size_t)p * 2048, jq, tt, vec);
  float4 wv = *(const float4*)(iw + p * 16 + 4 * jq);
  float partial = vec[0] * wv.x;
  partial = fmaf(vec[1], wv.y, partial);
  partial = fmaf(vec[2], wv.z, partial);
  partial = fmaf(vec[3], wv.w, partial);
  partial += qperm<0xB1>(partial);  // xor 1
  partial += qperm<0x4E>(partial);  // xor 2
  return fmaxf(partial, 0.0f);
}

// ---------------------------------------------------------------------------
// Staged level kernel (round-2 proven). Block = 256 thr = 4 waves = 4
// consecutive patches of one patch-row. Stage all params into LDS, compute
// with A from LDS. Input x: [cell][16b]. Output: [p][16b].
// ---------------------------------------------------------------------------
#define OFF_IA 0      // 4 x 2048
#define OFF_IV 8192   // 4 x 16
#define OFF_IW 8256   // 4 x 16
#define OFF_DA 8320   // 10 slots x 132 (128 + 4 pad -> bank spread)
#define OFF_DV 9640   // 10 x 4
#define OFF_DW 9680   // 10 x 16
#define LDS_TOT 9840  // floats = 39360 B -> 4 blocks/CU

template <int H>
__global__ __launch_bounds__(256) void level_kernel(
    const float* __restrict__ xT, float* __restrict__ hn,
    const float* __restrict__ dA, const float* __restrict__ dv,
    const float* __restrict__ dw, const float* __restrict__ iA,
    const float* __restrict__ iv, const float* __restrict__ iw) {
  constexpr int W2 = H / 2, NH = (H - 2) / 2;
  __shared__ __align__(16) float lds[LDS_TOT];
  float4* l4 = (float4*)lds;
  const int tid = threadIdx.x;
  const int p0 = blockIdx.x * 4;
  const int pi = p0 / W2, pj0 = p0 % W2;
  const int jq = tid & 3, b = (tid >> 2) & 15, w = tid >> 6;
  const int pj = pj0 + w;
  const int r = 2 * pi + (jq >> 1), c = 2 * pj + (jq & 1);
  const bool border = (r == 0) | (r == H - 1) | (c == 0) | (c == H - 1);
  const int dpi = (r - 1) >> 1, dpj = (c - 1) >> 1;

  // ---- pre-load x values (latency hides under staging)
  float xv0, xv1, xv2, xv3;
  if (border) {
    xv0 = xT[(r * H + c) * 16 + b];
  } else {
    int R0 = 1 + 2 * dpi, C0 = 1 + 2 * dpj;
    xv0 = xT[(R0 * H + C0) * 16 + b];
    xv1 = xT[(R0 * H + C0 + 1) * 16 + b];
    xv2 = xT[((R0 + 1) * H + C0) * 16 + b];
    xv3 = xT[((R0 + 1) * H + C0 + 1) * 16 + b];
  }

  // ---- stage phase -------------------------------------------------------
  {
    const float4* iA4 = (const float4*)iA + p0 * 512;
    float4 ra[8];
#pragma unroll
    for (int k = 0; k < 8; k++) ra[k] = iA4[tid + k * 256];

    float4 rd0, rd1;
    int sl0, gr0, sl1, gr1;
    const bool md1 = tid < 64;
    {
      int g = tid;
      int rs = g / 160, rem = g % 160, cs = rem / 32;
      gr0 = rem % 32;
      int di = min(max(pi - 1 + rs, 0), NH - 1);
      int dj = min(max(pj0 - 1 + cs, 0), NH - 1);
      sl0 = rs * 5 + cs;
      rd0 = *((const float4*)dA + (di * NH + dj) * 32 + gr0);
    }
    if (md1) {
      int g = tid + 256;
      int rs = g / 160, rem = g % 160, cs = rem / 32;
      gr1 = rem % 32;
      int di = min(max(pi - 1 + rs, 0), NH - 1);
      int dj = min(max(pj0 - 1 + cs, 0), NH - 1);
      sl1 = rs * 5 + cs;
      rd1 = *((const float4*)dA + (di * NH + dj) * 32 + gr1);
    }
    float4 rv;
    const bool mv = tid < 10;
    if (mv) {
      int rs = tid / 5, cs = tid % 5;
      int di = min(max(pi - 1 + rs, 0), NH - 1);
      int dj = min(max(pj0 - 1 + cs, 0), NH - 1);
      rv = *((const float4*)dv + (di * NH + dj));
    }
    float4 rw;
    const bool mw = tid < 40;
    if (mw) {
      int rs = tid / 20, rem = tid % 20, cs = rem / 4, gr = rem % 4;
      int di = min(max(pi - 1 + rs, 0), NH - 1);
      int dj = min(max(pj0 - 1 + cs, 0), NH - 1);
      rw = *((const float4*)dw + (di * NH + dj) * 4 + gr);
    }
    float4 rvv, rww;
    const bool mi = tid < 16;
    if (mi) {
      rvv = *((const float4*)iv + p0 * 4 + tid);
      rww = *((const float4*)iw + p0 * 4 + tid);
    }
#pragma unroll
    for (int k = 0; k < 8; k++) l4[OFF_IA / 4 + tid + k * 256] = ra[k];
    l4[OFF_DA / 4 + sl0 * 33 + gr0] = rd0;
    if (md1) l4[OFF_DA / 4 + sl1 * 33 + gr1] = rd1;
    if (mv) l4[OFF_DV / 4 + tid] = rv;
    if (mw) l4[OFF_DW / 4 + tid] = rw;
    if (mi) l4[OFF_IV / 4 + tid] = rvv;
    if (mi) l4[OFF_IW / 4 + tid] = rww;
  }
  __syncthreads();

  // ---- compute phase -----------------------------------------------------
  float tcell;
  if (border) {
    tcell = xv0;
  } else {
    int sd = ((r - 1) & 1) * 2 + ((c - 1) & 1);
    int slot = (dpi - pi + 1) * 5 + (dpj - pj0 + 1);
    const float4* Av = (const float4*)(lds + OFF_DA + slot * 132);
    float4 dvv = *(const float4*)(lds + OFF_DV + slot * 4);
    float v0 = dvv.x, v1 = dvv.y, v2 = dvv.z, v3 = dvv.w;
    float tins[4] = {xv0, xv1, xv2, xv3};
#pragma unroll
    for (int s = 0; s < 4; s++) {
      const float4* A0 = Av + s * 8;
      float4 q0 = {0.f, 0.f, 0.f, 0.f}, q1 = {0.f, 0.f, 0.f, 0.f};
      q0 = f4fma(v0, A0[0], q0);
      q0 = f4fma(v1, A0[1], q0);
      q0 = f4fma(v2, A0[2], q0);
      q0 = f4fma(v3, A0[3], q0);
      q1 = f4fma(v0, A0[4], q1);
      q1 = f4fma(v1, A0[5], q1);
      q1 = f4fma(v2, A0[6], q1);
      q1 = f4fma(v3, A0[7], q1);
      float ph = tins[s], om = 1.0f - ph;
      v0 = ph * q0.x + om * q1.x;
      v1 = ph * q0.y + om * q1.y;
      v2 = ph * q0.z + om * q1.z;
      v3 = ph * q0.w + om * q1.w;
    }
    const float* wp = lds + OFF_DW + slot * 16 + sd;
    float y = v0 * wp[0];
    y = fmaf(v1, wp[4], y);
    y = fmaf(v2, wp[8], y);
    y = fmaf(v3, wp[12], y);
    tcell = fmaxf(y, 0.0f);
  }
  float tt[4];
  tt[0] = qperm<0x00>(tcell);
  tt[1] = qperm<0x55>(tcell);
  tt[2] = qperm<0xAA>(tcell);
  tt[3] = qperm<0xFF>(tcell);
  float4 vv = *(const float4*)(lds + OFF_IV + w * 16 + 4 * jq);
  float vec[4] = {vv.x, vv.y, vv.z, vv.w};
  mps16_chain(lds + OFF_IA + w * 2048, jq, tt, vec);
  float4 wv = *(const float4*)(lds + OFF_IW + w * 16 + 4 * jq);
  float partial = vec[0] * wv.x;
  partial = fmaf(vec[1], wv.y, partial);
  partial = fmaf(vec[2], wv.z, partial);
  partial = fmaf(vec[3], wv.w, partial);
  partial += qperm<0xB1>(partial);
  partial += qperm<0x4E>(partial);
  if (jq == 0) hn[(p0 + w) * 16 + b] = fmaxf(partial, 0.0f);
}

// ---------------------------------------------------------------------------
// x transpose: [b][16384] -> [cell][b] so all level-kernel x reads coalesce.
// ---------------------------------------------------------------------------
__global__ __launch_bounds__(256) void transpose_kernel(
    const float* __restrict__ x, float* __restrict__ xT) {
  __shared__ float t[64][17];
  int tid = threadIdx.x;
  int c0 = blockIdx.x * 64;
  {
    int bb = tid >> 4, c4 = tid & 15;
    float4 v = *((const float4*)(x + bb * 16384 + c0) + c4);
    t[c4 * 4 + 0][bb] = v.x;
    t[c4 * 4 + 1][bb] = v.y;
    t[c4 * 4 + 2][bb] = v.z;
    t[c4 * 4 + 3][bb] = v.w;
  }
  __syncthreads();
  {
    int cl = tid >> 2, bq = tid & 3;
    float4 v;
    v.x = t[cl][bq * 4 + 0];
    v.y = t[cl][bq * 4 + 1];
    v.z = t[cl][bq * 4 + 2];
    v.w = t[cl][bq * 4 + 3];
    *((float4*)(xT + (c0 + cl) * 16) + bq) = v;
  }
}

// ---------------------------------------------------------------------------
// L6 + head kernel: ONE block, 256 threads. Stage i6A (32KB) + fA (8KB) +
// small params into LDS with full 256-thread parallelism, then L6 with all
// 256 lanes (16b x 4p x 4jq) and the head with 64 lanes.
// ---------------------------------------------------------------------------
struct Tail6Args {
  const float* h5;     // [16 cell][16 b]
  const float* in[9];  // d6A,d6v,d6w,i6A,i6v,i6w,fA,fv,fw
  float* out;
};

__global__ __launch_bounds__(256) void tail6_kernel(Tail6Args a) {
  __shared__ __align__(16) float s_i6A[8192];
  __shared__ __align__(16) float s_fA[2048];
  __shared__ __align__(16) float s_d6A[128];
  __shared__ __align__(16) float s_d6v[4];
  __shared__ __align__(16) float s_d6w[16];
  __shared__ __align__(16) float s_i6v[64];
  __shared__ __align__(16) float s_i6w[64];
  __shared__ float s_x6[256];  // [b][cell]
  __shared__ float s_h6[64];   // [b][4]
  const int tid = threadIdx.x;
  // ---- stage -------------------------------------------------------------
  {
    const float4* g = (const float4*)a.in[3];  // i6A: 2048 f4
    float4 ra[8];
#pragma unroll
    for (int k = 0; k < 8; k++) ra[k] = g[tid + k * 256];
    const float4* gf = (const float4*)a.in[6];  // fA: 512 f4
    float4 rf0 = gf[tid], rf1 = gf[tid + 256];
    float4 rdA;
    const bool mA = tid < 32;
    if (mA) rdA = ((const float4*)a.in[0])[tid];
    float4 rdv;
    if (tid == 0) rdv = ((const float4*)a.in[1])[0];
    float4 rdw;
    const bool mdw = tid < 4;
    if (mdw) rdw = ((const float4*)a.in[2])[tid];
    float4 riv, riw;
    const bool mi = tid < 16;
    if (mi) {
      riv = ((const float4*)a.in[4])[tid];
      riw = ((const float4*)a.in[5])[tid];
    }
    float xv = a.h5[tid];  // tid = cell*16 + b
#pragma unroll
    for (int k = 0; k < 8; k++) ((float4*)s_i6A)[tid + k * 256] = ra[k];
    ((float4*)s_fA)[tid] = rf0;
    ((float4*)s_fA)[tid + 256] = rf1;
    if (mA) ((float4*)s_d6A)[tid] = rdA;
    if (tid == 0) ((float4*)s_d6v)[0] = rdv;
    if (mdw) ((float4*)s_d6w)[tid] = rdw;
    if (mi) {
      ((float4*)s_i6v)[tid] = riv;
      ((float4*)s_i6w)[tid] = riw;
    }
    s_x6[(tid & 15) * 16 + (tid >> 4)] = xv;  // -> [b][cell]
  }
  __syncthreads();
  // ---- level 6: H=4, 16b x 4p x 4jq = 256 lanes --------------------------
  {
    int jq = tid & 3, p = (tid >> 2) & 3, b = tid >> 4;
    float o = fused_di_quad<4, 1>(s_x6 + b * 16, p, jq, s_d6A, s_d6v, s_d6w,
                                  s_i6A, s_i6v, s_i6w);
    if (jq == 0) s_h6[b * 4 + p] = o;
  }
  __syncthreads();
  // ---- final head: flat (2x2) -> 10 classes; 16b x 4jq = 64 lanes --------
  if (tid < 64) {
    int jq = tid & 3, b = tid >> 2;
    const float* fv = a.in[7];
    const float* fw = a.in[8];
    float tt[4] = {s_h6[b * 4 + 0], s_h6[b * 4 + 1], s_h6[b * 4 + 2],
                   s_h6[b * 4 + 3]};
    float4 vv = *(const float4*)(fv + 4 * jq);
    float vec[4] = {vv.x, vv.y, vv.z, vv.w};
    mps16_chain(s_fA, jq, tt, vec);
    float acc[10];
#pragma unroll
    for (int o = 0; o < 10; o++) acc[o] = 0.f;
#pragma unroll
    for (int k = 0; k < 4; k++)
#pragma unroll
      for (int o = 0; o < 10; o++)
        acc[o] = fmaf(vec[k], fw[(4 * jq + k) * 10 + o], acc[o]);
#pragma unroll
    for (int o = 0; o < 10; o++) {
      acc[o] += qperm<0xB1>(acc[o]);
      acc[o] += qperm<0x4E>(acc[o]);
    }
    if (jq == 0) {
#pragma unroll
      for (int o = 0; o < 10; o++) a.out[b * 10 + o] = fmaxf(acc[o], 0.0f);
    }
  }
}

extern "C" void kernel_launch(void* const* d_in, const int* in_sizes, int n_in,
                              void* d_out, int out_size, void* d_ws,
                              size_t ws_size, hipStream_t stream) {
  const float* x = (const float*)d_in[0];
  float* ws = (float*)d_ws;
  float* xT = ws;           // 16384 cells x 16 b = 262144
  float* h1 = xT + 262144;  // 4096 x 16
  float* h2 = h1 + 65536;   // 1024 x 16
  float* h3 = h2 + 16384;   //  256 x 16
  float* h4 = h3 + 4096;    //   64 x 16
  float* h5 = h4 + 1024;    //   16 x 16

  transpose_kernel<<<256, 256, 0, stream>>>(x, xT);
  // level 1: H=128, 4096 patches -> 1024 blocks
  level_kernel<128><<<1024, 256, 0, stream>>>(
      xT, h1, (const float*)d_in[1], (const float*)d_in[2],
      (const float*)d_in[3], (const float*)d_in[4], (const float*)d_in[5],
      (const float*)d_in[6]);
  // level 2: H=64, 1024 patches -> 256 blocks
  level_kernel<64><<<256, 256, 0, stream>>>(
      h1, h2, (const float*)d_in[7], (const float*)d_in[8],
      (const float*)d_in[9], (const float*)d_in[10], (const float*)d_in[11],
      (const float*)d_in[12]);
  // level 3: H=32, 256 patches -> 64 blocks
  level_kernel<32><<<64, 256, 0, stream>>>(
      h2, h3, (const float*)d_in[13], (const float*)d_in[14],
      (const float*)d_in[15], (const float*)d_in[16], (const float*)d_in[17],
      (const float*)d_in[18]);
  // level 4: H=16, 64 patches -> 16 blocks
  level_kernel<16><<<16, 256, 0, stream>>>(
      h3, h4, (const float*)d_in[19], (const float*)d_in[20],
      (const float*)d_in[21], (const float*)d_in[22], (const float*)d_in[23],
      (const float*)d_in[24]);
  // level 5: H=8, 16 patches -> 4 blocks (STAGED now, unlike round-2 tail)
  level_kernel<8><<<4, 256, 0, stream>>>(
      h4, h5, (const float*)d_in[25], (const float*)d_in[26],
      (const float*)d_in[27], (const float*)d_in[28], (const float*)d_in[29],
      (const float*)d_in[30]);
  // level 6 + head: one block, fully staged
  Tail6Args ta;
  ta.h5 = h5;
  for (int i = 0; i < 9; i++) ta.in[i] = (const float*)d_in[31 + i];
  ta.out = (float*)d_out;
  tail6_kernel<<<1, 256, 0, stream>>>(ta);
}